// Round 7
// baseline (190.144 us; speedup 1.0000x reference)
//
#include <hip/hip_runtime.h>
#include <math.h>

#define SEQLEN   2048
#define HIDDEN   1024
#define NMODES   32
#define CHANNELS 4096
#define CPB      64                  // channels per block
#define NBLK64   (CHANNELS / CPB)    // 64 channel-blocks

typedef float f2 __attribute__((ext_vector_type(2)));

// Packed fp32 math (full-rate). Inline asm so it cannot scalarize.
// VOP3P packed-f32 operands are 64-bit VGPR pairs - no scalar-reg broadcast.
__device__ __forceinline__ f2 pk_fma(f2 a, f2 b, f2 c) {
    f2 d; asm("v_pk_fma_f32 %0, %1, %2, %3" : "=v"(d) : "v"(a), "v"(b), "v"(c)); return d;
}
__device__ __forceinline__ f2 pk_mul(f2 a, f2 b) {
    f2 d; asm("v_pk_mul_f32 %0, %1, %2" : "=v"(d) : "v"(a), "v"(b)); return d;
}
template <int CTRL>
__device__ __forceinline__ float dpp_add(float p) {
    int t = __builtin_amdgcn_update_dpp(0, __float_as_int(p), CTRL, 0xF, 0xF, true);
    return p + __int_as_float(t);
}

// Bilinear (GBT alpha=0.5) discretization, with Cc = 2*(c0 + i c1) folded into B.
__device__ __forceinline__ void mode_coef_folded(
    float dt, float al, float aim, float br, float bi, float c0, float c1,
    float& adr, float& adi, float& bpr, float& bpi)
{
    const float hd = 0.5f * dt;
    const float ar = -expf(al);
    const float dr = 1.0f - hd * ar, di = -hd * aim;
    const float inv = 1.0f / (dr * dr + di * di);
    const float nr = 1.0f + hd * ar, ni = hd * aim;
    adr = (nr * dr + ni * di) * inv;
    adi = (ni * dr - nr * di) * inv;
    const float tbr = dt * br, tbi = dt * bi;
    const float bdr = (tbr * dr + tbi * di) * inv;
    const float bdi = (tbi * dr - tbr * di) * inv;
    const float cr = 2.f * c0, ci = 2.f * c1;
    bpr = cr * bdr - ci * bdi;
    bpi = cr * bdi + ci * bdr;
}

__device__ __forceinline__ void step4(const f2 Ar[4], const f2 Ai[4], const f2 nAi[4],
                                      const f2 Br[4], const f2 Bi[4],
                                      f2 vr[4], f2 vi[4], float uu)
{
    f2 u2; u2.x = uu; u2.y = uu;
    #pragma unroll
    for (int p = 0; p < 4; ++p) {
        f2 nr = pk_fma(Ar[p], vr[p], pk_fma(nAi[p], vi[p], pk_mul(Br[p], u2)));
        f2 ni = pk_fma(Ai[p], vr[p], pk_fma(Ar[p], vi[p], pk_mul(Bi[p], u2)));
        vr[p] = nr; vi[p] = ni;
    }
}

// Fused single-pass chunked scan with decoupled look-back.
// Block = 256 thr = 64 channels (4 lanes/channel, 8 modes/lane), one chunk.
// Grid = NBLK64 * NCT blocks; all co-resident at 4 blocks/CU (1024 = 4*256).
template <int NCT, int LOG2CL>
__global__ __launch_bounds__(256, 4) void ssm_fused(
    const float* __restrict__ input, const float* __restrict__ log_dt,
    const float* __restrict__ Dp, const float* __restrict__ A_log,
    const float* __restrict__ A_imag, const float* __restrict__ Bp,
    const float* __restrict__ Cp, int* __restrict__ flags,
    float* __restrict__ states,      // [ch][NCT-1][ r[32] | i[32] ]  (v-space)
    float* __restrict__ out)
{
    constexpr int CL = SEQLEN / NCT;
    const int tid   = threadIdx.x;
    const int ll    = tid & 3;                  // lane in 4-lane team (quad)
    const int team  = tid >> 2;                 // channel in block 0..63
    const int blk64 = blockIdx.x & (NBLK64 - 1);
    const int chunk = blockIdx.x >> 6;          // 0..NCT-1
    const int ch    = blk64 * CPB + team;
    const int h     = ch & (HIDDEN - 1);
    const int b     = ch >> 10;
    const int m0    = ll * 8;

    const float* ip = input + ((size_t)b * SEQLEN + (size_t)chunk * CL) * HIDDEN + h;

    // ---- per-lane coefficients (8 modes), C-folded ----
    f2 Ar[4], Ai[4], nAi[4], Br[4], Bi[4];
    {
        float adr[8], adi[8], bpr[8], bpi[8];
        const float dt = expf(log_dt[h]);
        const float* alp = A_log  + (size_t)h * NMODES + m0;
        const float* amp = A_imag + (size_t)h * NMODES + m0;
        const float* bp  = Bp + ((size_t)h * NMODES + m0) * 2;
        const float* cp  = Cp + ((size_t)h * NMODES + m0) * 2;
        #pragma unroll
        for (int k = 0; k < 8; ++k)
            mode_coef_folded(dt, alp[k], amp[k], bp[2*k], bp[2*k+1],
                             cp[2*k], cp[2*k+1], adr[k], adi[k], bpr[k], bpi[k]);
        #pragma unroll
        for (int p = 0; p < 4; ++p) {
            Ar[p]  = f2{adr[2*p], adr[2*p+1]};
            Ai[p]  = f2{adi[2*p], adi[2*p+1]};
            nAi[p] = f2{-adi[2*p], -adi[2*p+1]};
            Br[p]  = f2{bpr[2*p], bpr[2*p+1]};
            Bi[p]  = f2{bpi[2*p], bpi[2*p+1]};
        }
    }

    // ---- pass 1: local chunk scan from 0 (producers: chunks 0..NCT-2) ----
    if (chunk < NCT - 1) {
        f2 xr[4], xi[4];
        #pragma unroll
        for (int p = 0; p < 4; ++p) { xr[p] = f2{0.f,0.f}; xi[p] = f2{0.f,0.f}; }
        float ua[8], ub[8];
        #pragma unroll
        for (int j = 0; j < 8; ++j) ua[j] = ip[(size_t)j * HIDDEN];
        #pragma unroll 1
        for (int t0 = 0; t0 < CL; t0 += 16) {
            #pragma unroll
            for (int j = 0; j < 8; ++j) ub[j] = ip[(size_t)(t0 + 8 + j) * HIDDEN];
            #pragma unroll
            for (int j = 0; j < 8; ++j) step4(Ar, Ai, nAi, Br, Bi, xr, xi, ua[j]);
            if (t0 + 16 < CL) {
                #pragma unroll
                for (int j = 0; j < 8; ++j) ua[j] = ip[(size_t)(t0 + 16 + j) * HIDDEN];
            }
            #pragma unroll
            for (int j = 0; j < 8; ++j) step4(Ar, Ai, nAi, Br, Bi, xr, xi, ub[j]);
        }
        float* sp = states + ((size_t)ch * (NCT - 1) + chunk) * 64;
        *(float4*)(sp + m0)          = make_float4(xr[0].x, xr[0].y, xr[1].x, xr[1].y);
        *(float4*)(sp + m0 + 4)      = make_float4(xr[2].x, xr[2].y, xr[3].x, xr[3].y);
        *(float4*)(sp + 32 + m0)     = make_float4(xi[0].x, xi[0].y, xi[1].x, xi[1].y);
        *(float4*)(sp + 32 + m0 + 4) = make_float4(xi[2].x, xi[2].y, xi[3].x, xi[3].y);
        __syncthreads();
        if (tid == 0) {
            __threadfence();
            __hip_atomic_store(&flags[chunk * NBLK64 + blk64], 1,
                               __ATOMIC_RELEASE, __HIP_MEMORY_SCOPE_AGENT);
        }
    }

    // ---- look-back: combine predecessors' local states into carry ----
    f2 vr[4], vi[4];
    #pragma unroll
    for (int p = 0; p < 4; ++p) { vr[p] = f2{0.f,0.f}; vi[p] = f2{0.f,0.f}; }
    if (chunk > 0) {
        if (tid == 0) {
            for (int c2 = 0; c2 < chunk; ++c2)
                while (__hip_atomic_load(&flags[c2 * NBLK64 + blk64],
                                         __ATOMIC_ACQUIRE, __HIP_MEMORY_SCOPE_AGENT) == 0)
                    __builtin_amdgcn_s_sleep(2);
        }
        __syncthreads();
        // Apow = A^CL by repeated squaring
        f2 Pr[4], Pi[4], nPi[4];
        #pragma unroll
        for (int p = 0; p < 4; ++p) { Pr[p] = Ar[p]; Pi[p] = Ai[p]; }
        #pragma unroll
        for (int s = 0; s < LOG2CL; ++s) {
            #pragma unroll
            for (int p = 0; p < 4; ++p) {
                f2 npr = Pr[p] * Pr[p] - Pi[p] * Pi[p];
                f2 npi = Pr[p] * Pi[p]; npi = npi + npi;
                Pr[p] = npr; Pi[p] = npi;
            }
        }
        #pragma unroll
        for (int p = 0; p < 4; ++p) nPi[p] = f2{-Pi[p].x, -Pi[p].y};
        // Horner over previous chunk-end local states (v-space)
        const float* spb = states + (size_t)ch * (NCT - 1) * 64;
        for (int c2 = 0; c2 < chunk; ++c2) {
            const float* sp = spb + (size_t)c2 * 64;
            const float4 R0 = *(const float4*)(sp + m0);
            const float4 R1 = *(const float4*)(sp + m0 + 4);
            const float4 I0 = *(const float4*)(sp + 32 + m0);
            const float4 I1 = *(const float4*)(sp + 32 + m0 + 4);
            f2 sr[4] = { f2{R0.x,R0.y}, f2{R0.z,R0.w}, f2{R1.x,R1.y}, f2{R1.z,R1.w} };
            f2 si[4] = { f2{I0.x,I0.y}, f2{I0.z,I0.w}, f2{I1.x,I1.y}, f2{I1.z,I1.w} };
            #pragma unroll
            for (int p = 0; p < 4; ++p) {
                f2 nr = pk_fma(Pr[p], vr[p], pk_fma(nPi[p], vi[p], sr[p]));
                f2 ni = pk_fma(Pi[p], vr[p], pk_fma(Pr[p], vi[p], si[p]));
                vr[p] = nr; vi[p] = ni;
            }
        }
    }

    // ---- pass 2: y scan with carry ----
    const float Dh = Dp[h];
    float* op = out + ((size_t)b * SEQLEN + (size_t)chunk * CL) * HIDDEN + h;
    const bool wr = (ll == 0);
    float ua[8], ub[8];
    #pragma unroll
    for (int j = 0; j < 8; ++j) ua[j] = ip[(size_t)j * HIDDEN];
    #pragma unroll 1
    for (int t0 = 0; t0 < CL; t0 += 16) {
        #pragma unroll
        for (int j = 0; j < 8; ++j) ub[j] = ip[(size_t)(t0 + 8 + j) * HIDDEN];
        #pragma unroll
        for (int j = 0; j < 8; ++j) {
            const float uu = ua[j];
            step4(Ar, Ai, nAi, Br, Bi, vr, vi, uu);
            f2 s2 = (vr[0] + vr[1]) + (vr[2] + vr[3]);
            float pp = s2.x + s2.y;
            pp = dpp_add<0xB1>(pp);     // quad xor1
            pp = dpp_add<0x4E>(pp);     // quad xor2 -> full 4-lane (32-mode) sum
            if (wr) op[(size_t)(t0 + j) * HIDDEN] = fmaf(Dh, uu, pp);
        }
        if (t0 + 16 < CL) {
            #pragma unroll
            for (int j = 0; j < 8; ++j) ua[j] = ip[(size_t)(t0 + 16 + j) * HIDDEN];
        }
        #pragma unroll
        for (int j = 0; j < 8; ++j) {
            const float uu = ub[j];
            step4(Ar, Ai, nAi, Br, Bi, vr, vi, uu);
            f2 s2 = (vr[0] + vr[1]) + (vr[2] + vr[3]);
            float pp = s2.x + s2.y;
            pp = dpp_add<0xB1>(pp);
            pp = dpp_add<0x4E>(pp);
            if (wr) op[(size_t)(t0 + 8 + j) * HIDDEN] = fmaf(Dh, uu, pp);
        }
    }
}

extern "C" void kernel_launch(void* const* d_in, const int* in_sizes, int n_in,
                              void* d_out, int out_size, void* d_ws, size_t ws_size,
                              hipStream_t stream) {
    const float* input  = (const float*)d_in[0];
    const float* log_dt = (const float*)d_in[1];
    const float* Dp     = (const float*)d_in[2];
    const float* A_log  = (const float*)d_in[3];
    const float* A_imag = (const float*)d_in[4];
    const float* Bp     = (const float*)d_in[5];
    const float* Cp     = (const float*)d_in[6];
    float* out    = (float*)d_out;
    int*   flags  = (int*)d_ws;
    float* states = (float*)((char*)d_ws + 4096);

    auto need = [](int nc) {
        return (size_t)4096 + (size_t)CHANNELS * (nc - 1) * 64 * sizeof(float);
    };
    hipMemsetAsync(d_ws, 0, 4096, stream);   // reset look-back flags every call
    if (ws_size >= need(16)) {
        ssm_fused<16, 7><<<dim3(NBLK64 * 16), dim3(256), 0, stream>>>(
            input, log_dt, Dp, A_log, A_imag, Bp, Cp, flags, states, out);
    } else {
        ssm_fused<8, 8><<<dim3(NBLK64 * 8), dim3(256), 0, stream>>>(
            input, log_dt, Dp, A_log, A_imag, Bp, Cp, flags, states, out);
    }
}

// Round 8
// 116.577 us; speedup vs baseline: 1.6311x; 1.6311x over previous
//
#include <hip/hip_runtime.h>
#include <math.h>

#define SEQLEN   2048
#define HIDDEN   1024
#define NMODES   32
#define CHANNELS 4096
#define CPB      64                  // channels per block (256 thr, 4 lanes/ch)
#define NBLK64   (CHANNELS / CPB)    // 64 channel-blocks

typedef float f2 __attribute__((ext_vector_type(2)));

// Packed fp32 math (full-rate). Inline asm so it cannot scalarize.
__device__ __forceinline__ f2 pk_fma(f2 a, f2 b, f2 c) {
    f2 d; asm("v_pk_fma_f32 %0, %1, %2, %3" : "=v"(d) : "v"(a), "v"(b), "v"(c)); return d;
}
__device__ __forceinline__ f2 pk_mul(f2 a, f2 b) {
    f2 d; asm("v_pk_mul_f32 %0, %1, %2" : "=v"(d) : "v"(a), "v"(b)); return d;
}
template <int CTRL>
__device__ __forceinline__ float dpp_add(float p) {
    int t = __builtin_amdgcn_update_dpp(0, __float_as_int(p), CTRL, 0xF, 0xF, true);
    return p + __int_as_float(t);
}

// A_disc only (bilinear, alpha=0.5)
__device__ __forceinline__ void mode_A(float dt, float al, float aim,
                                       float& adr, float& adi)
{
    const float hd = 0.5f * dt;
    const float ar = -expf(al);
    const float dr = 1.0f - hd * ar, di = -hd * aim;
    const float inv = 1.0f / (dr * dr + di * di);
    const float nr = 1.0f + hd * ar, ni = hd * aim;
    adr = (nr * dr + ni * di) * inv;
    adi = (ni * dr - nr * di) * inv;
}

// A_disc + B' = Cc .* B_disc  (C folded)
__device__ __forceinline__ void mode_coef_folded(
    float dt, float al, float aim, float br, float bi, float c0, float c1,
    float& adr, float& adi, float& bpr, float& bpi)
{
    const float hd = 0.5f * dt;
    const float ar = -expf(al);
    const float dr = 1.0f - hd * ar, di = -hd * aim;
    const float inv = 1.0f / (dr * dr + di * di);
    const float nr = 1.0f + hd * ar, ni = hd * aim;
    adr = (nr * dr + ni * di) * inv;
    adi = (ni * dr - nr * di) * inv;
    const float tbr = dt * br, tbi = dt * bi;
    const float bdr = (tbr * dr + tbi * di) * inv;
    const float bdi = (tbi * dr - tbr * di) * inv;
    const float cr = 2.f * c0, ci = 2.f * c1;
    bpr = cr * bdr - ci * bdi;
    bpi = cr * bdi + ci * bdr;
}

__device__ __forceinline__ void load_coefs_folded(
    const float* __restrict__ log_dt, const float* __restrict__ A_log,
    const float* __restrict__ A_imag, const float* __restrict__ Bp,
    const float* __restrict__ Cp, int h, int m0,
    f2 Ar[4], f2 Ai[4], f2 nAi[4], f2 Br[4], f2 Bi[4])
{
    float adr[8], adi[8], bpr[8], bpi[8];
    const float dt = expf(log_dt[h]);
    const float* alp = A_log  + (size_t)h * NMODES + m0;
    const float* amp = A_imag + (size_t)h * NMODES + m0;
    const float* bp  = Bp + ((size_t)h * NMODES + m0) * 2;
    const float* cp  = Cp + ((size_t)h * NMODES + m0) * 2;
    #pragma unroll
    for (int k = 0; k < 8; ++k)
        mode_coef_folded(dt, alp[k], amp[k], bp[2*k], bp[2*k+1],
                         cp[2*k], cp[2*k+1], adr[k], adi[k], bpr[k], bpi[k]);
    #pragma unroll
    for (int p = 0; p < 4; ++p) {
        Ar[p]  = f2{adr[2*p], adr[2*p+1]};
        Ai[p]  = f2{adi[2*p], adi[2*p+1]};
        nAi[p] = f2{-adi[2*p], -adi[2*p+1]};
        Br[p]  = f2{bpr[2*p], bpr[2*p+1]};
        Bi[p]  = f2{bpi[2*p], bpi[2*p+1]};
    }
}

__device__ __forceinline__ void step4(const f2 Ar[4], const f2 Ai[4], const f2 nAi[4],
                                      const f2 Br[4], const f2 Bi[4],
                                      f2 vr[4], f2 vi[4], float uu)
{
    f2 u2; u2.x = uu; u2.y = uu;
    #pragma unroll
    for (int p = 0; p < 4; ++p) {
        f2 nr = pk_fma(Ar[p], vr[p], pk_fma(nAi[p], vi[p], pk_mul(Br[p], u2)));
        f2 ni = pk_fma(Ai[p], vr[p], pk_fma(Ar[p], vi[p], pk_mul(Bi[p], u2)));
        vr[p] = nr; vi[p] = ni;
    }
}

// ---- Kernel 1: local chunk v-scans from 0, chunks 0..NCT-2 ---------------
// Block = 256 thr = 64 channels; grid = 64 * (NCT-1).
template <int NCT>
__global__ void ssm_local(
    const float* __restrict__ input, const float* __restrict__ log_dt,
    const float* __restrict__ A_log, const float* __restrict__ A_imag,
    const float* __restrict__ Bp, const float* __restrict__ Cp,
    float* __restrict__ states)      // [ch][NCT-1][ r[32] | i[32] ]  (v-space)
{
    constexpr int CL = SEQLEN / NCT;
    const int tid   = threadIdx.x;
    const int ll    = tid & 3;
    const int team  = tid >> 2;
    const int blk64 = blockIdx.x & (NBLK64 - 1);
    const int chunk = blockIdx.x >> 6;          // 0..NCT-2
    const int ch    = blk64 * CPB + team;
    const int h     = ch & (HIDDEN - 1);
    const int b     = ch >> 10;
    const int m0    = ll * 8;

    const float* ip = input + ((size_t)b * SEQLEN + (size_t)chunk * CL) * HIDDEN + h;

    float ua[8], ub[8];
    #pragma unroll
    for (int j = 0; j < 8; ++j) ua[j] = ip[(size_t)j * HIDDEN];

    f2 Ar[4], Ai[4], nAi[4], Br[4], Bi[4];
    load_coefs_folded(log_dt, A_log, A_imag, Bp, Cp, h, m0, Ar, Ai, nAi, Br, Bi);

    f2 xr[4], xi[4];
    #pragma unroll
    for (int p = 0; p < 4; ++p) { xr[p] = f2{0.f,0.f}; xi[p] = f2{0.f,0.f}; }

    #pragma unroll 1
    for (int t0 = 0; t0 < CL; t0 += 16) {
        #pragma unroll
        for (int j = 0; j < 8; ++j) ub[j] = ip[(size_t)(t0 + 8 + j) * HIDDEN];
        #pragma unroll
        for (int j = 0; j < 8; ++j) step4(Ar, Ai, nAi, Br, Bi, xr, xi, ua[j]);
        if (t0 + 16 < CL) {
            #pragma unroll
            for (int j = 0; j < 8; ++j) ua[j] = ip[(size_t)(t0 + 16 + j) * HIDDEN];
        }
        #pragma unroll
        for (int j = 0; j < 8; ++j) step4(Ar, Ai, nAi, Br, Bi, xr, xi, ub[j]);
    }

    float* sp = states + ((size_t)ch * (NCT - 1) + chunk) * 64;
    *(float4*)(sp + m0)          = make_float4(xr[0].x, xr[0].y, xr[1].x, xr[1].y);
    *(float4*)(sp + m0 + 4)      = make_float4(xr[2].x, xr[2].y, xr[3].x, xr[3].y);
    *(float4*)(sp + 32 + m0)     = make_float4(xi[0].x, xi[0].y, xi[1].x, xi[1].y);
    *(float4*)(sp + 32 + m0 + 4) = make_float4(xi[2].x, xi[2].y, xi[3].x, xi[3].y);
}

// ---- Kernel 2 (tiny): in-place prefix over chunk states ------------------
// After this, slot c holds the TRUE state at end of chunk c (carry into c+1).
// One lane per (ch, 8 modes): 16384 threads.
template <int NCT, int LOG2CL>
__global__ void ssm_combine(
    const float* __restrict__ log_dt, const float* __restrict__ A_log,
    const float* __restrict__ A_imag, float* __restrict__ states)
{
    const int gid = blockIdx.x * 256 + threadIdx.x;
    const int ch  = gid >> 2;
    const int ll  = gid & 3;
    const int h   = ch & (HIDDEN - 1);
    const int m0  = ll * 8;

    // Apow = A_disc^CL
    f2 Pr[4], Pi[4], nPi[4];
    {
        float adr[8], adi[8];
        const float dt = expf(log_dt[h]);
        const float* alp = A_log  + (size_t)h * NMODES + m0;
        const float* amp = A_imag + (size_t)h * NMODES + m0;
        #pragma unroll
        for (int k = 0; k < 8; ++k) mode_A(dt, alp[k], amp[k], adr[k], adi[k]);
        #pragma unroll
        for (int p = 0; p < 4; ++p) { Pr[p] = f2{adr[2*p], adr[2*p+1]}; Pi[p] = f2{adi[2*p], adi[2*p+1]}; }
        #pragma unroll
        for (int s = 0; s < LOG2CL; ++s) {
            #pragma unroll
            for (int p = 0; p < 4; ++p) {
                f2 npr = Pr[p] * Pr[p] - Pi[p] * Pi[p];
                f2 npi = Pr[p] * Pi[p]; npi = npi + npi;
                Pr[p] = npr; Pi[p] = npi;
            }
        }
        #pragma unroll
        for (int p = 0; p < 4; ++p) nPi[p] = f2{-Pi[p].x, -Pi[p].y};
    }

    float* spb = states + (size_t)ch * (NCT - 1) * 64;

    // X = S_0 (slot 0 already correct)
    f2 Xr[4], Xi[4];
    {
        const float4 R0 = *(const float4*)(spb + m0);
        const float4 R1 = *(const float4*)(spb + m0 + 4);
        const float4 I0 = *(const float4*)(spb + 32 + m0);
        const float4 I1 = *(const float4*)(spb + 32 + m0 + 4);
        Xr[0] = f2{R0.x,R0.y}; Xr[1] = f2{R0.z,R0.w}; Xr[2] = f2{R1.x,R1.y}; Xr[3] = f2{R1.z,R1.w};
        Xi[0] = f2{I0.x,I0.y}; Xi[1] = f2{I0.z,I0.w}; Xi[2] = f2{I1.x,I1.y}; Xi[3] = f2{I1.z,I1.w};
    }

    // prefetch-1-ahead serial prefix
    for (int c = 1; c < NCT - 1; ++c) {
        float* sp = spb + (size_t)c * 64;
        const float4 R0 = *(const float4*)(sp + m0);
        const float4 R1 = *(const float4*)(sp + m0 + 4);
        const float4 I0 = *(const float4*)(sp + 32 + m0);
        const float4 I1 = *(const float4*)(sp + 32 + m0 + 4);
        f2 sr[4] = { f2{R0.x,R0.y}, f2{R0.z,R0.w}, f2{R1.x,R1.y}, f2{R1.z,R1.w} };
        f2 si[4] = { f2{I0.x,I0.y}, f2{I0.z,I0.w}, f2{I1.x,I1.y}, f2{I1.z,I1.w} };
        #pragma unroll
        for (int p = 0; p < 4; ++p) {
            f2 nr = pk_fma(Pr[p], Xr[p], pk_fma(nPi[p], Xi[p], sr[p]));
            f2 ni = pk_fma(Pi[p], Xr[p], pk_fma(Pr[p], Xi[p], si[p]));
            Xr[p] = nr; Xi[p] = ni;
        }
        *(float4*)(sp + m0)          = make_float4(Xr[0].x, Xr[0].y, Xr[1].x, Xr[1].y);
        *(float4*)(sp + m0 + 4)      = make_float4(Xr[2].x, Xr[2].y, Xr[3].x, Xr[3].y);
        *(float4*)(sp + 32 + m0)     = make_float4(Xi[0].x, Xi[0].y, Xi[1].x, Xi[1].y);
        *(float4*)(sp + 32 + m0 + 4) = make_float4(Xi[2].x, Xi[2].y, Xi[3].x, Xi[3].y);
    }
}

// ---- Kernel 3: y-scan per chunk with loaded carry ------------------------
template <int NCT>
__global__ void ssm_scan2(
    const float* __restrict__ input, const float* __restrict__ log_dt,
    const float* __restrict__ Dp, const float* __restrict__ A_log,
    const float* __restrict__ A_imag, const float* __restrict__ Bp,
    const float* __restrict__ Cp, const float* __restrict__ states,
    float* __restrict__ out)
{
    constexpr int CL = SEQLEN / NCT;
    const int tid   = threadIdx.x;
    const int ll    = tid & 3;
    const int team  = tid >> 2;
    const int blk64 = blockIdx.x & (NBLK64 - 1);
    const int chunk = blockIdx.x >> 6;          // 0..NCT-1
    const int ch    = blk64 * CPB + team;
    const int h     = ch & (HIDDEN - 1);
    const int b     = ch >> 10;
    const int m0    = ll * 8;

    const float* ip = input + ((size_t)b * SEQLEN + (size_t)chunk * CL) * HIDDEN + h;

    float ua[8], ub[8];
    #pragma unroll
    for (int j = 0; j < 8; ++j) ua[j] = ip[(size_t)j * HIDDEN];

    f2 Ar[4], Ai[4], nAi[4], Br[4], Bi[4];
    load_coefs_folded(log_dt, A_log, A_imag, Bp, Cp, h, m0, Ar, Ai, nAi, Br, Bi);

    // carry = true state at end of chunk-1 (v-space)
    f2 vr[4], vi[4];
    if (chunk > 0) {
        const float* sp = states + ((size_t)ch * (NCT - 1) + (chunk - 1)) * 64;
        const float4 R0 = *(const float4*)(sp + m0);
        const float4 R1 = *(const float4*)(sp + m0 + 4);
        const float4 I0 = *(const float4*)(sp + 32 + m0);
        const float4 I1 = *(const float4*)(sp + 32 + m0 + 4);
        vr[0] = f2{R0.x,R0.y}; vr[1] = f2{R0.z,R0.w}; vr[2] = f2{R1.x,R1.y}; vr[3] = f2{R1.z,R1.w};
        vi[0] = f2{I0.x,I0.y}; vi[1] = f2{I0.z,I0.w}; vi[2] = f2{I1.x,I1.y}; vi[3] = f2{I1.z,I1.w};
    } else {
        #pragma unroll
        for (int p = 0; p < 4; ++p) { vr[p] = f2{0.f,0.f}; vi[p] = f2{0.f,0.f}; }
    }

    const float Dh = Dp[h];
    float* op = out + ((size_t)b * SEQLEN + (size_t)chunk * CL) * HIDDEN + h;
    const bool wr = (ll == 0);

    #pragma unroll 1
    for (int t0 = 0; t0 < CL; t0 += 16) {
        #pragma unroll
        for (int j = 0; j < 8; ++j) ub[j] = ip[(size_t)(t0 + 8 + j) * HIDDEN];
        #pragma unroll
        for (int j = 0; j < 8; ++j) {
            const float uu = ua[j];
            step4(Ar, Ai, nAi, Br, Bi, vr, vi, uu);
            f2 s2 = (vr[0] + vr[1]) + (vr[2] + vr[3]);
            float pp = s2.x + s2.y;
            pp = dpp_add<0xB1>(pp);     // quad xor1
            pp = dpp_add<0x4E>(pp);     // quad xor2 -> 32-mode sum in all 4 lanes
            if (wr) op[(size_t)(t0 + j) * HIDDEN] = fmaf(Dh, uu, pp);
        }
        if (t0 + 16 < CL) {
            #pragma unroll
            for (int j = 0; j < 8; ++j) ua[j] = ip[(size_t)(t0 + 16 + j) * HIDDEN];
        }
        #pragma unroll
        for (int j = 0; j < 8; ++j) {
            const float uu = ub[j];
            step4(Ar, Ai, nAi, Br, Bi, vr, vi, uu);
            f2 s2 = (vr[0] + vr[1]) + (vr[2] + vr[3]);
            float pp = s2.x + s2.y;
            pp = dpp_add<0xB1>(pp);
            pp = dpp_add<0x4E>(pp);
            if (wr) op[(size_t)(t0 + 8 + j) * HIDDEN] = fmaf(Dh, uu, pp);
        }
    }
}

template <int NCT, int LOG2CL>
static void launch_all(const float* input, const float* log_dt, const float* Dp,
                       const float* A_log, const float* A_imag, const float* Bp,
                       const float* Cp, float* states, float* out,
                       hipStream_t stream) {
    ssm_local<NCT><<<dim3(NBLK64 * (NCT - 1)), dim3(256), 0, stream>>>(
        input, log_dt, A_log, A_imag, Bp, Cp, states);
    ssm_combine<NCT, LOG2CL><<<dim3(CHANNELS * 4 / 256), dim3(256), 0, stream>>>(
        log_dt, A_log, A_imag, states);
    ssm_scan2<NCT><<<dim3(NBLK64 * NCT), dim3(256), 0, stream>>>(
        input, log_dt, Dp, A_log, A_imag, Bp, Cp, states, out);
}

extern "C" void kernel_launch(void* const* d_in, const int* in_sizes, int n_in,
                              void* d_out, int out_size, void* d_ws, size_t ws_size,
                              hipStream_t stream) {
    const float* input  = (const float*)d_in[0];
    const float* log_dt = (const float*)d_in[1];
    const float* Dp     = (const float*)d_in[2];
    const float* A_log  = (const float*)d_in[3];
    const float* A_imag = (const float*)d_in[4];
    const float* Bp     = (const float*)d_in[5];
    const float* Cp     = (const float*)d_in[6];
    float* out    = (float*)d_out;
    float* states = (float*)d_ws;

    auto need = [](int nc) {
        return (size_t)CHANNELS * (nc - 1) * 64 * sizeof(float);
    };
    if (ws_size >= need(32))
        launch_all<32, 6>(input, log_dt, Dp, A_log, A_imag, Bp, Cp, states, out, stream);
    else if (ws_size >= need(16))
        launch_all<16, 7>(input, log_dt, Dp, A_log, A_imag, Bp, Cp, states, out, stream);
    else
        launch_all<8, 8>(input, log_dt, Dp, A_log, A_imag, Bp, Cp, states, out, stream);
}

// Round 9
// 115.567 us; speedup vs baseline: 1.6453x; 1.0087x over previous
//
#include <hip/hip_runtime.h>
#include <math.h>

#define SEQLEN   2048
#define HIDDEN   1024
#define NMODES   32
#define CHANNELS 4096
#define CPB      64                  // channels per block (256 thr, 4 lanes/ch)
#define NBLK64   (CHANNELS / CPB)    // 64 channel-blocks

typedef float f2 __attribute__((ext_vector_type(2)));

// Packed fp32 math (full-rate). Inline asm so it cannot scalarize.
__device__ __forceinline__ f2 pk_fma(f2 a, f2 b, f2 c) {
    f2 d; asm("v_pk_fma_f32 %0, %1, %2, %3" : "=v"(d) : "v"(a), "v"(b), "v"(c)); return d;
}
__device__ __forceinline__ f2 pk_mul(f2 a, f2 b) {
    f2 d; asm("v_pk_mul_f32 %0, %1, %2" : "=v"(d) : "v"(a), "v"(b)); return d;
}
__device__ __forceinline__ f2 pk_add(f2 a, f2 b) {
    f2 d; asm("v_pk_add_f32 %0, %1, %2" : "=v"(d) : "v"(a), "v"(b)); return d;
}
template <int CTRL>
__device__ __forceinline__ float dpp_add(float p) {
    int t = __builtin_amdgcn_update_dpp(0, __float_as_int(p), CTRL, 0xF, 0xF, true);
    return p + __int_as_float(t);
}

// A_disc only (bilinear, alpha=0.5)
__device__ __forceinline__ void mode_A(float dt, float al, float aim,
                                       float& adr, float& adi)
{
    const float hd = 0.5f * dt;
    const float ar = -expf(al);
    const float dr = 1.0f - hd * ar, di = -hd * aim;
    const float inv = 1.0f / (dr * dr + di * di);
    const float nr = 1.0f + hd * ar, ni = hd * aim;
    adr = (nr * dr + ni * di) * inv;
    adi = (ni * dr - nr * di) * inv;
}

// A_disc + B' = Cc .* B_disc  (C folded)
__device__ __forceinline__ void mode_coef_folded(
    float dt, float al, float aim, float br, float bi, float c0, float c1,
    float& adr, float& adi, float& bpr, float& bpi)
{
    const float hd = 0.5f * dt;
    const float ar = -expf(al);
    const float dr = 1.0f - hd * ar, di = -hd * aim;
    const float inv = 1.0f / (dr * dr + di * di);
    const float nr = 1.0f + hd * ar, ni = hd * aim;
    adr = (nr * dr + ni * di) * inv;
    adi = (ni * dr - nr * di) * inv;
    const float tbr = dt * br, tbi = dt * bi;
    const float bdr = (tbr * dr + tbi * di) * inv;
    const float bdi = (tbi * dr - tbr * di) * inv;
    const float cr = 2.f * c0, ci = 2.f * c1;
    bpr = cr * bdr - ci * bdi;
    bpi = cr * bdi + ci * bdr;
}

__device__ __forceinline__ void load_coefs_folded(
    const float* __restrict__ log_dt, const float* __restrict__ A_log,
    const float* __restrict__ A_imag, const float* __restrict__ Bp,
    const float* __restrict__ Cp, int h, int m0,
    f2 Ar[4], f2 Ai[4], f2 nAi[4], f2 Br[4], f2 Bi[4])
{
    float adr[8], adi[8], bpr[8], bpi[8];
    const float dt = expf(log_dt[h]);
    const float* alp = A_log  + (size_t)h * NMODES + m0;
    const float* amp = A_imag + (size_t)h * NMODES + m0;
    const float* bp  = Bp + ((size_t)h * NMODES + m0) * 2;
    const float* cp  = Cp + ((size_t)h * NMODES + m0) * 2;
    #pragma unroll
    for (int k = 0; k < 8; ++k)
        mode_coef_folded(dt, alp[k], amp[k], bp[2*k], bp[2*k+1],
                         cp[2*k], cp[2*k+1], adr[k], adi[k], bpr[k], bpi[k]);
    #pragma unroll
    for (int p = 0; p < 4; ++p) {
        Ar[p]  = f2{adr[2*p], adr[2*p+1]};
        Ai[p]  = f2{adi[2*p], adi[2*p+1]};
        nAi[p] = f2{-adi[2*p], -adi[2*p+1]};
        Br[p]  = f2{bpr[2*p], bpr[2*p+1]};
        Bi[p]  = f2{bpi[2*p], bpi[2*p+1]};
    }
}

__device__ __forceinline__ void step4(const f2 Ar[4], const f2 Ai[4], const f2 nAi[4],
                                      const f2 Br[4], const f2 Bi[4],
                                      f2 vr[4], f2 vi[4], float uu)
{
    f2 u2; u2.x = uu; u2.y = uu;
    #pragma unroll
    for (int p = 0; p < 4; ++p) {
        f2 nr = pk_fma(Ar[p], vr[p], pk_fma(nAi[p], vi[p], pk_mul(Br[p], u2)));
        f2 ni = pk_fma(Ai[p], vr[p], pk_fma(Ar[p], vi[p], pk_mul(Bi[p], u2)));
        vr[p] = nr; vi[p] = ni;
    }
}

// Stage a [CL][64] input tile into LDS with coalesced dwordx4 loads.
template <int CL>
__device__ __forceinline__ void stage_tile(
    const float* __restrict__ gbase, float (*tile)[64], int tid)
{
    #pragma unroll
    for (int r = 0; r < CL / 16; ++r) {
        const int t  = r * 16 + (tid >> 4);
        const int c4 = (tid & 15) * 4;
        const float4 g = *(const float4*)(gbase + (size_t)t * HIDDEN + c4);
        *(float4*)&tile[t][c4] = g;
    }
    __syncthreads();
}

// ---- Kernel 1: local chunk v-scans from 0, chunks 0..NCT-2 ---------------
template <int NCT>
__global__ void ssm_local(
    const float* __restrict__ input, const float* __restrict__ log_dt,
    const float* __restrict__ A_log, const float* __restrict__ A_imag,
    const float* __restrict__ Bp, const float* __restrict__ Cp,
    float* __restrict__ states)      // [ch][NCT-1][ r[32] | i[32] ]  (v-space)
{
    constexpr int CL = SEQLEN / NCT;
    __shared__ float tile[CL][64];
    const int tid   = threadIdx.x;
    const int ll    = tid & 3;
    const int team  = tid >> 2;                 // channel-in-block 0..63
    const int blk64 = blockIdx.x & (NBLK64 - 1);
    const int chunk = blockIdx.x >> 6;          // 0..NCT-2
    const int ch    = blk64 * CPB + team;
    const int h     = ch & (HIDDEN - 1);
    const int b     = ch >> 10;
    const int m0    = ll * 8;
    const int h0    = (blk64 * CPB) & (HIDDEN - 1);
    const int b0    = (blk64 * CPB) >> 10;

    stage_tile<CL>(input + ((size_t)b0 * SEQLEN + (size_t)chunk * CL) * HIDDEN + h0,
                   tile, tid);

    f2 Ar[4], Ai[4], nAi[4], Br[4], Bi[4];
    load_coefs_folded(log_dt, A_log, A_imag, Bp, Cp, h, m0, Ar, Ai, nAi, Br, Bi);

    f2 xr[4], xi[4];
    #pragma unroll
    for (int p = 0; p < 4; ++p) { xr[p] = f2{0.f,0.f}; xi[p] = f2{0.f,0.f}; }

    #pragma unroll 1
    for (int t0 = 0; t0 < CL; t0 += 16) {
        #pragma unroll
        for (int j = 0; j < 16; ++j)
            step4(Ar, Ai, nAi, Br, Bi, xr, xi, tile[t0 + j][team]);
    }

    float* sp = states + ((size_t)ch * (NCT - 1) + chunk) * 64;
    *(float4*)(sp + m0)          = make_float4(xr[0].x, xr[0].y, xr[1].x, xr[1].y);
    *(float4*)(sp + m0 + 4)      = make_float4(xr[2].x, xr[2].y, xr[3].x, xr[3].y);
    *(float4*)(sp + 32 + m0)     = make_float4(xi[0].x, xi[0].y, xi[1].x, xi[1].y);
    *(float4*)(sp + 32 + m0 + 4) = make_float4(xi[2].x, xi[2].y, xi[3].x, xi[3].y);
}

// ---- Kernel 2 (tiny): in-place prefix over chunk states ------------------
template <int NCT, int LOG2CL>
__global__ void ssm_combine(
    const float* __restrict__ log_dt, const float* __restrict__ A_log,
    const float* __restrict__ A_imag, float* __restrict__ states)
{
    const int gid = blockIdx.x * 256 + threadIdx.x;
    const int ch  = gid >> 2;
    const int ll  = gid & 3;
    const int h   = ch & (HIDDEN - 1);
    const int m0  = ll * 8;

    f2 Pr[4], Pi[4], nPi[4];
    {
        float adr[8], adi[8];
        const float dt = expf(log_dt[h]);
        const float* alp = A_log  + (size_t)h * NMODES + m0;
        const float* amp = A_imag + (size_t)h * NMODES + m0;
        #pragma unroll
        for (int k = 0; k < 8; ++k) mode_A(dt, alp[k], amp[k], adr[k], adi[k]);
        #pragma unroll
        for (int p = 0; p < 4; ++p) { Pr[p] = f2{adr[2*p], adr[2*p+1]}; Pi[p] = f2{adi[2*p], adi[2*p+1]}; }
        #pragma unroll
        for (int s = 0; s < LOG2CL; ++s) {
            #pragma unroll
            for (int p = 0; p < 4; ++p) {
                f2 npr = Pr[p] * Pr[p] - Pi[p] * Pi[p];
                f2 npi = Pr[p] * Pi[p]; npi = npi + npi;
                Pr[p] = npr; Pi[p] = npi;
            }
        }
        #pragma unroll
        for (int p = 0; p < 4; ++p) nPi[p] = f2{-Pi[p].x, -Pi[p].y};
    }

    float* spb = states + (size_t)ch * (NCT - 1) * 64;

    f2 Xr[4], Xi[4];
    {
        const float4 R0 = *(const float4*)(spb + m0);
        const float4 R1 = *(const float4*)(spb + m0 + 4);
        const float4 I0 = *(const float4*)(spb + 32 + m0);
        const float4 I1 = *(const float4*)(spb + 32 + m0 + 4);
        Xr[0] = f2{R0.x,R0.y}; Xr[1] = f2{R0.z,R0.w}; Xr[2] = f2{R1.x,R1.y}; Xr[3] = f2{R1.z,R1.w};
        Xi[0] = f2{I0.x,I0.y}; Xi[1] = f2{I0.z,I0.w}; Xi[2] = f2{I1.x,I1.y}; Xi[3] = f2{I1.z,I1.w};
    }

    for (int c = 1; c < NCT - 1; ++c) {
        float* sp = spb + (size_t)c * 64;
        const float4 R0 = *(const float4*)(sp + m0);
        const float4 R1 = *(const float4*)(sp + m0 + 4);
        const float4 I0 = *(const float4*)(sp + 32 + m0);
        const float4 I1 = *(const float4*)(sp + 32 + m0 + 4);
        f2 sr[4] = { f2{R0.x,R0.y}, f2{R0.z,R0.w}, f2{R1.x,R1.y}, f2{R1.z,R1.w} };
        f2 si[4] = { f2{I0.x,I0.y}, f2{I0.z,I0.w}, f2{I1.x,I1.y}, f2{I1.z,I1.w} };
        #pragma unroll
        for (int p = 0; p < 4; ++p) {
            f2 nr = pk_fma(Pr[p], Xr[p], pk_fma(nPi[p], Xi[p], sr[p]));
            f2 ni = pk_fma(Pi[p], Xr[p], pk_fma(Pr[p], Xi[p], si[p]));
            Xr[p] = nr; Xi[p] = ni;
        }
        *(float4*)(sp + m0)          = make_float4(Xr[0].x, Xr[0].y, Xr[1].x, Xr[1].y);
        *(float4*)(sp + m0 + 4)      = make_float4(Xr[2].x, Xr[2].y, Xr[3].x, Xr[3].y);
        *(float4*)(sp + 32 + m0)     = make_float4(Xi[0].x, Xi[0].y, Xi[1].x, Xi[1].y);
        *(float4*)(sp + 32 + m0 + 4) = make_float4(Xi[2].x, Xi[2].y, Xi[3].x, Xi[3].y);
    }
}

// ---- Kernel 3: y-scan per chunk with loaded carry ------------------------
template <int NCT>
__global__ void ssm_scan2(
    const float* __restrict__ input, const float* __restrict__ log_dt,
    const float* __restrict__ Dp, const float* __restrict__ A_log,
    const float* __restrict__ A_imag, const float* __restrict__ Bp,
    const float* __restrict__ Cp, const float* __restrict__ states,
    float* __restrict__ out)
{
    constexpr int CL = SEQLEN / NCT;
    __shared__ float tile[CL][64];
    const int tid   = threadIdx.x;
    const int ll    = tid & 3;
    const int team  = tid >> 2;
    const int blk64 = blockIdx.x & (NBLK64 - 1);
    const int chunk = blockIdx.x >> 6;          // 0..NCT-1
    const int ch    = blk64 * CPB + team;
    const int h     = ch & (HIDDEN - 1);
    const int b     = ch >> 10;
    const int m0    = ll * 8;
    const int h0    = (blk64 * CPB) & (HIDDEN - 1);
    const int b0    = (blk64 * CPB) >> 10;

    stage_tile<CL>(input + ((size_t)b0 * SEQLEN + (size_t)chunk * CL) * HIDDEN + h0,
                   tile, tid);

    f2 Ar[4], Ai[4], nAi[4], Br[4], Bi[4];
    load_coefs_folded(log_dt, A_log, A_imag, Bp, Cp, h, m0, Ar, Ai, nAi, Br, Bi);

    // carry = true state at end of chunk-1 (v-space)
    f2 vr[4], vi[4];
    if (chunk > 0) {
        const float* sp = states + ((size_t)ch * (NCT - 1) + (chunk - 1)) * 64;
        const float4 R0 = *(const float4*)(sp + m0);
        const float4 R1 = *(const float4*)(sp + m0 + 4);
        const float4 I0 = *(const float4*)(sp + 32 + m0);
        const float4 I1 = *(const float4*)(sp + 32 + m0 + 4);
        vr[0] = f2{R0.x,R0.y}; vr[1] = f2{R0.z,R0.w}; vr[2] = f2{R1.x,R1.y}; vr[3] = f2{R1.z,R1.w};
        vi[0] = f2{I0.x,I0.y}; vi[1] = f2{I0.z,I0.w}; vi[2] = f2{I1.x,I1.y}; vi[3] = f2{I1.z,I1.w};
    } else {
        #pragma unroll
        for (int p = 0; p < 4; ++p) { vr[p] = f2{0.f,0.f}; vi[p] = f2{0.f,0.f}; }
    }

    const float Dh = Dp[h];
    float* op = out + ((size_t)b * SEQLEN + (size_t)chunk * CL) * HIDDEN + h;
    const bool wr = (ll == 0);

    #pragma unroll 1
    for (int t0 = 0; t0 < CL; t0 += 16) {
        #pragma unroll
        for (int j = 0; j < 16; ++j) {
            const float uu = tile[t0 + j][team];
            step4(Ar, Ai, nAi, Br, Bi, vr, vi, uu);
            f2 s01 = pk_add(vr[0], vr[1]);
            f2 s23 = pk_add(vr[2], vr[3]);
            f2 s2  = pk_add(s01, s23);
            float pp = s2.x + s2.y;
            pp = dpp_add<0xB1>(pp);     // quad xor1
            pp = dpp_add<0x4E>(pp);     // quad xor2 -> 32-mode sum in all 4 lanes
            if (wr) *op = fmaf(Dh, uu, pp);
            op += HIDDEN;               // incremental pointer, no per-step addr derive
        }
    }
}

template <int NCT, int LOG2CL>
static void launch_all(const float* input, const float* log_dt, const float* Dp,
                       const float* A_log, const float* A_imag, const float* Bp,
                       const float* Cp, float* states, float* out,
                       hipStream_t stream) {
    ssm_local<NCT><<<dim3(NBLK64 * (NCT - 1)), dim3(256), 0, stream>>>(
        input, log_dt, A_log, A_imag, Bp, Cp, states);
    ssm_combine<NCT, LOG2CL><<<dim3(CHANNELS * 4 / 256), dim3(256), 0, stream>>>(
        log_dt, A_log, A_imag, states);
    ssm_scan2<NCT><<<dim3(NBLK64 * NCT), dim3(256), 0, stream>>>(
        input, log_dt, Dp, A_log, A_imag, Bp, Cp, states, out);
}

extern "C" void kernel_launch(void* const* d_in, const int* in_sizes, int n_in,
                              void* d_out, int out_size, void* d_ws, size_t ws_size,
                              hipStream_t stream) {
    const float* input  = (const float*)d_in[0];
    const float* log_dt = (const float*)d_in[1];
    const float* Dp     = (const float*)d_in[2];
    const float* A_log  = (const float*)d_in[3];
    const float* A_imag = (const float*)d_in[4];
    const float* Bp     = (const float*)d_in[5];
    const float* Cp     = (const float*)d_in[6];
    float* out    = (float*)d_out;
    float* states = (float*)d_ws;

    auto need = [](int nc) {
        return (size_t)CHANNELS * (nc - 1) * 64 * sizeof(float);
    };
    if (ws_size >= need(32))
        launch_all<32, 6>(input, log_dt, Dp, A_log, A_imag, Bp, Cp, states, out, stream);
    else if (ws_size >= need(16))
        launch_all<16, 7>(input, log_dt, Dp, A_log, A_imag, Bp, Cp, states, out, stream);
    else
        launch_all<8, 8>(input, log_dt, Dp, A_log, A_imag, Bp, Cp, states, out, stream);
}

// Round 10
// 103.723 us; speedup vs baseline: 1.8332x; 1.1142x over previous
//
#include <hip/hip_runtime.h>
#include <math.h>

#define SEQLEN   2048
#define HIDDEN   1024
#define NMODES   32
#define CHANNELS 4096
#define CPB      64                  // channels per block (256 thr, 4 lanes/ch)
#define NBLK64   (CHANNELS / CPB)    // 64 channel-blocks

typedef float f2 __attribute__((ext_vector_type(2)));

// Packed fp32 math (FLOP-parity with scalar but half the issue slots).
__device__ __forceinline__ f2 pk_fma(f2 a, f2 b, f2 c) {
    f2 d; asm("v_pk_fma_f32 %0, %1, %2, %3" : "=v"(d) : "v"(a), "v"(b), "v"(c)); return d;
}
__device__ __forceinline__ f2 pk_mul(f2 a, f2 b) {
    f2 d; asm("v_pk_mul_f32 %0, %1, %2" : "=v"(d) : "v"(a), "v"(b)); return d;
}
__device__ __forceinline__ f2 pk_add(f2 a, f2 b) {
    f2 d; asm("v_pk_add_f32 %0, %1, %2" : "=v"(d) : "v"(a), "v"(b)); return d;
}
template <int CTRL>
__device__ __forceinline__ float dpp_add(float p) {
    int t = __builtin_amdgcn_update_dpp(0, __float_as_int(p), CTRL, 0xF, 0xF, true);
    return p + __int_as_float(t);
}

// A_disc only (bilinear, alpha=0.5)
__device__ __forceinline__ void mode_A(float dt, float al, float aim,
                                       float& adr, float& adi)
{
    const float hd = 0.5f * dt;
    const float ar = -expf(al);
    const float dr = 1.0f - hd * ar, di = -hd * aim;
    const float inv = 1.0f / (dr * dr + di * di);
    const float nr = 1.0f + hd * ar, ni = hd * aim;
    adr = (nr * dr + ni * di) * inv;
    adi = (ni * dr - nr * di) * inv;
}

// A_disc + B' = Cc .* B_disc  (C folded)
__device__ __forceinline__ void mode_coef_folded(
    float dt, float al, float aim, float br, float bi, float c0, float c1,
    float& adr, float& adi, float& bpr, float& bpi)
{
    const float hd = 0.5f * dt;
    const float ar = -expf(al);
    const float dr = 1.0f - hd * ar, di = -hd * aim;
    const float inv = 1.0f / (dr * dr + di * di);
    const float nr = 1.0f + hd * ar, ni = hd * aim;
    adr = (nr * dr + ni * di) * inv;
    adi = (ni * dr - nr * di) * inv;
    const float tbr = dt * br, tbi = dt * bi;
    const float bdr = (tbr * dr + tbi * di) * inv;
    const float bdi = (tbi * dr - tbr * di) * inv;
    const float cr = 2.f * c0, ci = 2.f * c1;
    bpr = cr * bdr - ci * bdi;
    bpi = cr * bdi + ci * bdr;
}

__device__ __forceinline__ void load_coefs_folded(
    const float* __restrict__ log_dt, const float* __restrict__ A_log,
    const float* __restrict__ A_imag, const float* __restrict__ Bp,
    const float* __restrict__ Cp, int h, int m0,
    f2 Ar[4], f2 Ai[4], f2 nAi[4], f2 Br[4], f2 Bi[4])
{
    float adr[8], adi[8], bpr[8], bpi[8];
    const float dt = expf(log_dt[h]);
    const float* alp = A_log  + (size_t)h * NMODES + m0;
    const float* amp = A_imag + (size_t)h * NMODES + m0;
    const float* bp  = Bp + ((size_t)h * NMODES + m0) * 2;
    const float* cp  = Cp + ((size_t)h * NMODES + m0) * 2;
    #pragma unroll
    for (int k = 0; k < 8; ++k)
        mode_coef_folded(dt, alp[k], amp[k], bp[2*k], bp[2*k+1],
                         cp[2*k], cp[2*k+1], adr[k], adi[k], bpr[k], bpi[k]);
    #pragma unroll
    for (int p = 0; p < 4; ++p) {
        Ar[p]  = f2{adr[2*p], adr[2*p+1]};
        Ai[p]  = f2{adi[2*p], adi[2*p+1]};
        nAi[p] = f2{-adi[2*p], -adi[2*p+1]};
        Br[p]  = f2{bpr[2*p], bpr[2*p+1]};
        Bi[p]  = f2{bpi[2*p], bpi[2*p+1]};
    }
}

__device__ __forceinline__ void step4(const f2 Ar[4], const f2 Ai[4], const f2 nAi[4],
                                      const f2 Br[4], const f2 Bi[4],
                                      f2 vr[4], f2 vi[4], float uu)
{
    f2 u2; u2.x = uu; u2.y = uu;
    #pragma unroll
    for (int p = 0; p < 4; ++p) {
        f2 nr = pk_fma(Ar[p], vr[p], pk_fma(nAi[p], vi[p], pk_mul(Br[p], u2)));
        f2 ni = pk_fma(Ai[p], vr[p], pk_fma(Ar[p], vi[p], pk_mul(Bi[p], u2)));
        vr[p] = nr; vi[p] = ni;
    }
}

// Stage a [CL][64] input tile into LDS with coalesced dwordx4 loads.
template <int CL>
__device__ __forceinline__ void stage_tile(
    const float* __restrict__ gbase, float (*tile)[64], int tid)
{
    #pragma unroll
    for (int r = 0; r < CL / 16; ++r) {
        const int t  = r * 16 + (tid >> 4);
        const int c4 = (tid & 15) * 4;
        const float4 g = *(const float4*)(gbase + (size_t)t * HIDDEN + c4);
        *(float4*)&tile[t][c4] = g;
    }
    __syncthreads();
}

// ---- Kernel 1: local chunk states, K=4 STEP-BATCHED ----------------------
// x_{t+4} = A^4 x + G3 u0 + G2 u1 + G1 u2 + G0 u3, G_k = A^k * B'.
// 12 pk per mode-pair per 4 steps (vs 24 unbatched).
template <int NCT>
__global__ void ssm_local(
    const float* __restrict__ input, const float* __restrict__ log_dt,
    const float* __restrict__ A_log, const float* __restrict__ A_imag,
    const float* __restrict__ Bp, const float* __restrict__ Cp,
    float* __restrict__ states)      // [ch][NCT-1][ r[32] | i[32] ]  (v-space)
{
    constexpr int CL = SEQLEN / NCT;
    __shared__ float tile[CL][64];
    const int tid   = threadIdx.x;
    const int ll    = tid & 3;
    const int team  = tid >> 2;
    const int blk64 = blockIdx.x & (NBLK64 - 1);
    const int chunk = blockIdx.x >> 6;          // 0..NCT-2
    const int ch    = blk64 * CPB + team;
    const int h     = ch & (HIDDEN - 1);
    const int m0    = ll * 8;
    const int h0    = (blk64 * CPB) & (HIDDEN - 1);
    const int b0    = (blk64 * CPB) >> 10;

    stage_tile<CL>(input + ((size_t)b0 * SEQLEN + (size_t)chunk * CL) * HIDDEN + h0,
                   tile, tid);

    f2 Ar[4], Ai[4], nAi[4], Br[4], Bi[4];
    load_coefs_folded(log_dt, A_log, A_imag, Bp, Cp, h, m0, Ar, Ai, nAi, Br, Bi);

    // precompute G0..G3 and A^4 (one-time, plain f2 arith)
    f2 G1r[4], G1i[4], G2r[4], G2i[4], G3r[4], G3i[4];
    f2 A4r[4], A4i[4], nA4i[4];
    #pragma unroll
    for (int p = 0; p < 4; ++p) {
        G1r[p] = Ar[p]*Br[p] - Ai[p]*Bi[p];  G1i[p] = Ar[p]*Bi[p] + Ai[p]*Br[p];
        G2r[p] = Ar[p]*G1r[p] - Ai[p]*G1i[p]; G2i[p] = Ar[p]*G1i[p] + Ai[p]*G1r[p];
        G3r[p] = Ar[p]*G2r[p] - Ai[p]*G2i[p]; G3i[p] = Ar[p]*G2i[p] + Ai[p]*G2r[p];
        f2 A2r = Ar[p]*Ar[p] - Ai[p]*Ai[p];
        f2 A2i = Ar[p]*Ai[p]; A2i = A2i + A2i;
        A4r[p] = A2r*A2r - A2i*A2i;
        A4i[p] = A2r*A2i; A4i[p] = A4i[p] + A4i[p];
        nA4i[p] = f2{-A4i[p].x, -A4i[p].y};
    }

    f2 xr[4], xi[4];
    #pragma unroll
    for (int p = 0; p < 4; ++p) { xr[p] = f2{0.f,0.f}; xi[p] = f2{0.f,0.f}; }

    #pragma unroll 2
    for (int t0 = 0; t0 < CL; t0 += 4) {
        const float u0 = tile[t0 + 0][team];
        const float u1 = tile[t0 + 1][team];
        const float u2 = tile[t0 + 2][team];
        const float u3 = tile[t0 + 3][team];
        f2 U0; U0.x = u0; U0.y = u0;
        f2 U1; U1.x = u1; U1.y = u1;
        f2 U2; U2.x = u2; U2.y = u2;
        f2 U3; U3.x = u3; U3.y = u3;
        #pragma unroll
        for (int p = 0; p < 4; ++p) {
            f2 Sr = pk_fma(G1r[p], U2, pk_fma(G2r[p], U1, pk_mul(G3r[p], U0)));
            Sr = pk_fma(Br[p], U3, Sr);
            f2 Si = pk_fma(G1i[p], U2, pk_fma(G2i[p], U1, pk_mul(G3i[p], U0)));
            Si = pk_fma(Bi[p], U3, Si);
            f2 nr = pk_fma(A4r[p], xr[p], pk_fma(nA4i[p], xi[p], Sr));
            f2 ni = pk_fma(A4i[p], xr[p], pk_fma(A4r[p], xi[p], Si));
            xr[p] = nr; xi[p] = ni;
        }
    }

    float* sp = states + ((size_t)ch * (NCT - 1) + chunk) * 64;
    *(float4*)(sp + m0)          = make_float4(xr[0].x, xr[0].y, xr[1].x, xr[1].y);
    *(float4*)(sp + m0 + 4)      = make_float4(xr[2].x, xr[2].y, xr[3].x, xr[3].y);
    *(float4*)(sp + 32 + m0)     = make_float4(xi[0].x, xi[0].y, xi[1].x, xi[1].y);
    *(float4*)(sp + 32 + m0 + 4) = make_float4(xi[2].x, xi[2].y, xi[3].x, xi[3].y);
}

// ---- Kernel 2 (tiny): in-place prefix over chunk states ------------------
template <int NCT, int LOG2CL>
__global__ void ssm_combine(
    const float* __restrict__ log_dt, const float* __restrict__ A_log,
    const float* __restrict__ A_imag, float* __restrict__ states)
{
    const int gid = blockIdx.x * 256 + threadIdx.x;
    const int ch  = gid >> 2;
    const int ll  = gid & 3;
    const int h   = ch & (HIDDEN - 1);
    const int m0  = ll * 8;

    f2 Pr[4], Pi[4], nPi[4];
    {
        float adr[8], adi[8];
        const float dt = expf(log_dt[h]);
        const float* alp = A_log  + (size_t)h * NMODES + m0;
        const float* amp = A_imag + (size_t)h * NMODES + m0;
        #pragma unroll
        for (int k = 0; k < 8; ++k) mode_A(dt, alp[k], amp[k], adr[k], adi[k]);
        #pragma unroll
        for (int p = 0; p < 4; ++p) { Pr[p] = f2{adr[2*p], adr[2*p+1]}; Pi[p] = f2{adi[2*p], adi[2*p+1]}; }
        #pragma unroll
        for (int s = 0; s < LOG2CL; ++s) {
            #pragma unroll
            for (int p = 0; p < 4; ++p) {
                f2 npr = Pr[p] * Pr[p] - Pi[p] * Pi[p];
                f2 npi = Pr[p] * Pi[p]; npi = npi + npi;
                Pr[p] = npr; Pi[p] = npi;
            }
        }
        #pragma unroll
        for (int p = 0; p < 4; ++p) nPi[p] = f2{-Pi[p].x, -Pi[p].y};
    }

    float* spb = states + (size_t)ch * (NCT - 1) * 64;

    f2 Xr[4], Xi[4];
    {
        const float4 R0 = *(const float4*)(spb + m0);
        const float4 R1 = *(const float4*)(spb + m0 + 4);
        const float4 I0 = *(const float4*)(spb + 32 + m0);
        const float4 I1 = *(const float4*)(spb + 32 + m0 + 4);
        Xr[0] = f2{R0.x,R0.y}; Xr[1] = f2{R0.z,R0.w}; Xr[2] = f2{R1.x,R1.y}; Xr[3] = f2{R1.z,R1.w};
        Xi[0] = f2{I0.x,I0.y}; Xi[1] = f2{I0.z,I0.w}; Xi[2] = f2{I1.x,I1.y}; Xi[3] = f2{I1.z,I1.w};
    }

    for (int c = 1; c < NCT - 1; ++c) {
        float* sp = spb + (size_t)c * 64;
        const float4 R0 = *(const float4*)(sp + m0);
        const float4 R1 = *(const float4*)(sp + m0 + 4);
        const float4 I0 = *(const float4*)(sp + 32 + m0);
        const float4 I1 = *(const float4*)(sp + 32 + m0 + 4);
        f2 sr[4] = { f2{R0.x,R0.y}, f2{R0.z,R0.w}, f2{R1.x,R1.y}, f2{R1.z,R1.w} };
        f2 si[4] = { f2{I0.x,I0.y}, f2{I0.z,I0.w}, f2{I1.x,I1.y}, f2{I1.z,I1.w} };
        #pragma unroll
        for (int p = 0; p < 4; ++p) {
            f2 nr = pk_fma(Pr[p], Xr[p], pk_fma(nPi[p], Xi[p], sr[p]));
            f2 ni = pk_fma(Pi[p], Xr[p], pk_fma(Pr[p], Xi[p], si[p]));
            Xr[p] = nr; Xi[p] = ni;
        }
        *(float4*)(sp + m0)          = make_float4(Xr[0].x, Xr[0].y, Xr[1].x, Xr[1].y);
        *(float4*)(sp + m0 + 4)      = make_float4(Xr[2].x, Xr[2].y, Xr[3].x, Xr[3].y);
        *(float4*)(sp + 32 + m0)     = make_float4(Xi[0].x, Xi[0].y, Xi[1].x, Xi[1].y);
        *(float4*)(sp + 32 + m0 + 4) = make_float4(Xi[2].x, Xi[2].y, Xi[3].x, Xi[3].y);
    }
}

// ---- Kernel 3: y-scan per chunk; y staged to LDS, coalesced flush --------
template <int NCT>
__global__ void ssm_scan2(
    const float* __restrict__ input, const float* __restrict__ log_dt,
    const float* __restrict__ Dp, const float* __restrict__ A_log,
    const float* __restrict__ A_imag, const float* __restrict__ Bp,
    const float* __restrict__ Cp, const float* __restrict__ states,
    float* __restrict__ out)
{
    constexpr int CL = SEQLEN / NCT;
    __shared__ float tile[CL][64];
    const int tid   = threadIdx.x;
    const int ll    = tid & 3;
    const int team  = tid >> 2;
    const int blk64 = blockIdx.x & (NBLK64 - 1);
    const int chunk = blockIdx.x >> 6;          // 0..NCT-1
    const int ch    = blk64 * CPB + team;
    const int h     = ch & (HIDDEN - 1);
    const int m0    = ll * 8;
    const int h0    = (blk64 * CPB) & (HIDDEN - 1);
    const int b0    = (blk64 * CPB) >> 10;

    stage_tile<CL>(input + ((size_t)b0 * SEQLEN + (size_t)chunk * CL) * HIDDEN + h0,
                   tile, tid);

    f2 Ar[4], Ai[4], nAi[4], Br[4], Bi[4];
    load_coefs_folded(log_dt, A_log, A_imag, Bp, Cp, h, m0, Ar, Ai, nAi, Br, Bi);

    // carry = true state at end of chunk-1 (v-space)
    f2 vr[4], vi[4];
    if (chunk > 0) {
        const float* sp = states + ((size_t)ch * (NCT - 1) + (chunk - 1)) * 64;
        const float4 R0 = *(const float4*)(sp + m0);
        const float4 R1 = *(const float4*)(sp + m0 + 4);
        const float4 I0 = *(const float4*)(sp + 32 + m0);
        const float4 I1 = *(const float4*)(sp + 32 + m0 + 4);
        vr[0] = f2{R0.x,R0.y}; vr[1] = f2{R0.z,R0.w}; vr[2] = f2{R1.x,R1.y}; vr[3] = f2{R1.z,R1.w};
        vi[0] = f2{I0.x,I0.y}; vi[1] = f2{I0.z,I0.w}; vi[2] = f2{I1.x,I1.y}; vi[3] = f2{I1.z,I1.w};
    } else {
        #pragma unroll
        for (int p = 0; p < 4; ++p) { vr[p] = f2{0.f,0.f}; vi[p] = f2{0.f,0.f}; }
    }

    const float Dh = Dp[h];
    const bool wr = (ll == 0);

    // y written back into the tile slot whose u was just consumed.
    // Safe: within a team the read precedes the write in wave program order;
    // no other team touches this column.
    #pragma unroll 1
    for (int t0 = 0; t0 < CL; t0 += 16) {
        #pragma unroll
        for (int j = 0; j < 16; ++j) {
            const float uu = tile[t0 + j][team];
            step4(Ar, Ai, nAi, Br, Bi, vr, vi, uu);
            f2 s01 = pk_add(vr[0], vr[1]);
            f2 s23 = pk_add(vr[2], vr[3]);
            f2 s2  = pk_add(s01, s23);
            float pp = s2.x + s2.y;
            pp = dpp_add<0xB1>(pp);     // quad xor1
            pp = dpp_add<0x4E>(pp);     // quad xor2 -> 32-mode sum in all 4 lanes
            if (wr) tile[t0 + j][team] = fmaf(Dh, uu, pp);
        }
    }

    __syncthreads();
    float* obase = out + ((size_t)b0 * SEQLEN + (size_t)chunk * CL) * HIDDEN + h0;
    #pragma unroll
    for (int r = 0; r < CL / 16; ++r) {
        const int t  = r * 16 + (tid >> 4);
        const int c4 = (tid & 15) * 4;
        *(float4*)(obase + (size_t)t * HIDDEN + c4) = *(float4*)&tile[t][c4];
    }
}

template <int NCT, int LOG2CL>
static void launch_all(const float* input, const float* log_dt, const float* Dp,
                       const float* A_log, const float* A_imag, const float* Bp,
                       const float* Cp, float* states, float* out,
                       hipStream_t stream) {
    ssm_local<NCT><<<dim3(NBLK64 * (NCT - 1)), dim3(256), 0, stream>>>(
        input, log_dt, A_log, A_imag, Bp, Cp, states);
    ssm_combine<NCT, LOG2CL><<<dim3(CHANNELS * 4 / 256), dim3(256), 0, stream>>>(
        log_dt, A_log, A_imag, states);
    ssm_scan2<NCT><<<dim3(NBLK64 * NCT), dim3(256), 0, stream>>>(
        input, log_dt, Dp, A_log, A_imag, Bp, Cp, states, out);
}

extern "C" void kernel_launch(void* const* d_in, const int* in_sizes, int n_in,
                              void* d_out, int out_size, void* d_ws, size_t ws_size,
                              hipStream_t stream) {
    const float* input  = (const float*)d_in[0];
    const float* log_dt = (const float*)d_in[1];
    const float* Dp     = (const float*)d_in[2];
    const float* A_log  = (const float*)d_in[3];
    const float* A_imag = (const float*)d_in[4];
    const float* Bp     = (const float*)d_in[5];
    const float* Cp     = (const float*)d_in[6];
    float* out    = (float*)d_out;
    float* states = (float*)d_ws;

    auto need = [](int nc) {
        return (size_t)CHANNELS * (nc - 1) * 64 * sizeof(float);
    };
    if (ws_size >= need(32))
        launch_all<32, 6>(input, log_dt, Dp, A_log, A_imag, Bp, Cp, states, out, stream);
    else if (ws_size >= need(16))
        launch_all<16, 7>(input, log_dt, Dp, A_log, A_imag, Bp, Cp, states, out, stream);
    else
        launch_all<8, 8>(input, log_dt, Dp, A_log, A_imag, Bp, Cp, states, out, stream);
}